// Round 5
// baseline (470.527 us; speedup 1.0000x reference)
//
#include <hip/hip_runtime.h>
#include <hip/hip_cooperative_groups.h>

namespace cg = cooperative_groups;

#define NROWS 4096
#define NDOM 8

typedef short short8 __attribute__((ext_vector_type(8)));
typedef float floatx4 __attribute__((ext_vector_type(4)));
typedef unsigned short ushort8v __attribute__((ext_vector_type(8)));

__device__ __forceinline__ unsigned short f2bf(float f) {
    union { float f; unsigned u; } v; v.f = f;
    unsigned r = v.u + 0x7FFFu + ((v.u >> 16) & 1u);  // RNE
    return (unsigned short)(r >> 16);
}

// async global->LDS, 16B per lane; dest = wave-uniform base + lane*16,
// source address may be per-lane (gather is legal on the source side).
__device__ __forceinline__ void dma16(const void* g, void* l) {
    __builtin_amdgcn_global_load_lds(
        (const __attribute__((address_space(1))) unsigned*)g,
        (__attribute__((address_space(3))) unsigned*)l, 16, 0, 0);
}

// counted vmcnt wait (immediate must be a literal in the asm string)
template <int N>
__device__ __forceinline__ void wait_vmcnt() {
    static_assert(N == 0 || N == 2 || N == 3 || N == 4, "unsupported vmcnt");
    if constexpr (N == 0) asm volatile("s_waitcnt vmcnt(0)" ::: "memory");
    else if constexpr (N == 2) asm volatile("s_waitcnt vmcnt(2)" ::: "memory");
    else if constexpr (N == 3) asm volatile("s_waitcnt vmcnt(3)" ::: "memory");
    else if constexpr (N == 4) asm volatile("s_waitcnt vmcnt(4)" ::: "memory");
}

// ---------------------------------------------------------------------------
// weff transpose tile (512-thread version): (domain d, 64 n, 256 k) of
// bf16(sk*dk) -> wt[d][n][k]. Uses 32KB LDS.
// ---------------------------------------------------------------------------
template <int K, int N>
__device__ __forceinline__ void weff_tile(const float* __restrict__ sk,
                                          const float* __restrict__ dk,
                                          unsigned short* __restrict__ wt,
                                          unsigned short* __restrict__ lds,
                                          int local) {
    const int d = local & 7;
    const int rest = local >> 3;
    const int k0 = (rest & (K / 256 - 1)) * 256;
    const int n0 = (rest / (K / 256)) * 64;
    const int t = threadIdx.x;          // [0,512)

    // phase A: read n-coalesced, write LDS [n][k] with chunk-XOR swizzle
    const int n = t & 63;
    const int kg = (t >> 6) * 32;       // 8 k-groups of 32
#pragma unroll
    for (int c8 = 0; c8 < 4; ++c8) {    // 4 chunks of 8 k
        const int kb = k0 + kg + c8 * 8;
        unsigned short wb[8];
#pragma unroll
        for (int i = 0; i < 8; ++i) {
            int k = kb + i;
            wb[i] = f2bf(sk[(size_t)k * N + n0 + n] * dk[((size_t)d * K + k) * N + n0 + n]);
        }
        int ch = (kg + c8 * 8) >> 3;    // chunk index 0..31
        int phys = ch ^ (n & 31);
        *(ushort8v*)&lds[n * 256 + phys * 8] = *(ushort8v*)wb;
    }
    __syncthreads();

    // phase B: read LDS along k, store global [n][k] coalesced
#pragma unroll
    for (int it = 0; it < 2; ++it) {
        const int nn = (t >> 4) + it * 32;   // t>>4 in [0,32)
        const int c = t & 15;                // 32B unit = 2 chunks
        ushort8v a = *(ushort8v*)&lds[nn * 256 + ((2 * c) ^ (nn & 31)) * 8];
        ushort8v b = *(ushort8v*)&lds[nn * 256 + ((2 * c + 1) ^ (nn & 31)) * 8];
        unsigned short* dst = wt + ((size_t)d * N + n0 + nn) * K + k0 + c * 16;
        *(ushort8v*)dst = a;
        *(ushort8v*)(dst + 8) = b;
    }
}

// xb = bf16(x), original row order, 512 threads, b in [0,256) covers 16 rows.
__device__ __forceinline__ void xb_task(const float* __restrict__ x,
                                        unsigned short* __restrict__ xb, int b) {
    const int t = threadIdx.x;
#pragma unroll
    for (int pass = 0; pass < 4; ++pass) {
        int row = b * 16 + pass * 4 + (t >> 7);
        int ch = t & 127;                    // 8-elem chunk
        const float* src = x + (size_t)row * 1024 + ch * 8;
        floatx4 v0 = *(const floatx4*)src;
        floatx4 v1 = *(const floatx4*)(src + 4);
        unsigned short o[8];
        o[0] = f2bf(v0[0]); o[1] = f2bf(v0[1]); o[2] = f2bf(v0[2]); o[3] = f2bf(v0[3]);
        o[4] = f2bf(v1[0]); o[5] = f2bf(v1[1]); o[6] = f2bf(v1[2]); o[7] = f2bf(v1[3]);
        *(ushort8v*)(xb + (size_t)row * 1024 + ch * 8) = *(ushort8v*)o;
    }
}

struct SortMem {
    unsigned short cnt[256][NDOM];
    int base[256][NDOM];
    int dom_total[NDOM];
    int dom_off[NDOM + 1];
};

// deterministic stable counting sort; 512 threads present, 256 do the work,
// barriers are unconditional.
__device__ __forceinline__ void sort_task(const int* __restrict__ ind,
                                          int* __restrict__ offsets,
                                          int* __restrict__ rowidx,
                                          SortMem& s) {
    const int t = threadIdx.x;
    int myind[16];
    if (t < 256) {
#pragma unroll
        for (int i = 0; i < 16; ++i) myind[i] = ind[t * 16 + i];
        unsigned short c[NDOM];
#pragma unroll
        for (int d = 0; d < NDOM; ++d) c[d] = 0;
#pragma unroll
        for (int i = 0; i < 16; ++i) c[myind[i]]++;
#pragma unroll
        for (int d = 0; d < NDOM; ++d) s.cnt[t][d] = c[d];
    }
    __syncthreads();
    if (t < NDOM) {
        int acc = 0;
        for (int ch = 0; ch < 256; ++ch) { s.base[ch][t] = acc; acc += s.cnt[ch][t]; }
        s.dom_total[t] = acc;
    }
    __syncthreads();
    if (t == 0) {
        int acc = 0;
        for (int d = 0; d < NDOM; ++d) { s.dom_off[d] = acc; acc += s.dom_total[d]; }
        s.dom_off[NDOM] = acc;
    }
    __syncthreads();
    if (t < 256) {
        int pos[NDOM];
#pragma unroll
        for (int d = 0; d < NDOM; ++d) pos[d] = s.dom_off[d] + s.base[t][d];
#pragma unroll
        for (int i = 0; i < 16; ++i) {
            int dm = myind[i];
            rowidx[pos[dm]++] = t * 16 + i;
        }
        if (t <= NDOM) offsets[t] = s.dom_off[t];
    }
}

// ---------------------------------------------------------------------------
// Grouped GEMM body, 8 waves (WM=2 x WN=4), wave tile (FM*16)x(FN*16),
// block tile BM x BN, double-buffered LDS, counted-vmcnt pipeline.
// DMA instr slots (1KB each) are wave-strided; per-wave vmcnt matches the
// per-wave issue count (block-uniform branches only).
// ---------------------------------------------------------------------------
template <int FM, int FN, int MSLOTS, int K, int N, bool GATHER, bool SCATTER>
__device__ __forceinline__ void star_gemm_body(
        unsigned short* __restrict__ As,   // [2][BM*64]
        unsigned short* __restrict__ Ws,   // [2][BN*64]
        const unsigned short* __restrict__ Ab,
        const unsigned short* __restrict__ Wt,
        const float* __restrict__ sb,
        const float* __restrict__ db,
        float* __restrict__ OutF,
        unsigned short* __restrict__ OutB,
        const int* __restrict__ offsets,
        const int* __restrict__ rowidx,
        int gid) {
    constexpr int WM = 2, WN = 4, NW = 8;      // 8 waves, 512 threads
    constexpr int BM = WM * FM * 16;
    constexpr int BN = WN * FN * 16;
    constexpr int NK = K / 64;                 // 64-wide k tiles
    constexpr int AI_TOT = BM / 8;             // 1KB dma instrs for A k-tile
    constexpr int WI_TOT = BN / 8;
    constexpr int A_PER = AI_TOT / NW, A_REM = AI_TOT % NW;
    constexpr int W_PER = WI_TOT / NW;
    static_assert(WI_TOT % NW == 0, "W dma must be wave-uniform");
    constexpr int AI_MAX = (AI_TOT + NW - 1) / NW;
    constexpr int CNT = A_PER + W_PER;         // per-wave batch (w >= A_REM)
    constexpr int ASZ = BM * 64;
    constexpr int WSZ = BN * 64;

    const int d = gid & 7;                      // domain -> XCD round-robin
    const int mslot = (gid >> 3) % MSLOTS;
    const int n0 = (gid / (8 * MSLOTS)) * BN;

    const int bstart = offsets[d];
    const int bend = offsets[d + 1];
    const int bsize = bend - bstart;

    const int tid = threadIdx.x;
    const int lane = tid & 63;
    const int w = tid >> 6;        // [0,8)
    const int wy = w >> 2;         // [0,2)
    const int wx = w & 3;          // [0,4)
    const int lm = lane & 15;
    const int quad = lane >> 4;

    const int lrow = lane >> 3;    // DMA: row within 8-row group
    const int phys = lane & 7;     // DMA: physical LDS chunk

    float bias[FN];
#pragma unroll
    for (int j = 0; j < FN; ++j) {
        int n = n0 + wx * FN * 16 + j * 16 + lm;
        bias[j] = sb[n] + db[d * N + n];
    }

    // W dma sources (loop-invariant), wave-strided slots
    const unsigned short* wsrc[W_PER];
#pragma unroll
    for (int jj = 0; jj < W_PER; ++jj) {
        int j = w + jj * NW;
        int nn = j * 8 + lrow;
        int ch = phys ^ (nn & 7);
        wsrc[jj] = Wt + ((size_t)d * N + n0 + nn) * K + ch * 8;
    }

    for (int mt = mslot; mt * BM < bsize; mt += MSLOTS) {
        const int row_start = bstart + mt * BM;

        const unsigned short* asrc[AI_MAX];
#pragma unroll
        for (int jj = 0; jj < AI_MAX; ++jj) {
            int j = w + jj * NW;
            if (j < AI_TOT) {
                int mm = j * 8 + lrow;
                int ch = phys ^ (mm & 7);
                int p = row_start + mm; if (p >= bend) p = bend - 1;
                int src = GATHER ? rowidx[p] : p;
                asrc[jj] = Ab + (size_t)src * K + ch * 8;
            }
        }

        auto dma_tiles = [&](int kt, int buf) {
            const int k0 = kt * 64;
#pragma unroll
            for (int jj = 0; jj < AI_MAX; ++jj) {
                int j = w + jj * NW;
                if (j < AI_TOT) dma16(asrc[jj] + k0, &As[buf * ASZ + j * 512]);
            }
#pragma unroll
            for (int jj = 0; jj < W_PER; ++jj) {
                int j = w + jj * NW;
                dma16(wsrc[jj] + k0, &Ws[buf * WSZ + j * 512]);
            }
        };

        dma_tiles(0, 0);                       // prologue batch in flight

        floatx4 acc[FM][FN];
#pragma unroll
        for (int i = 0; i < FM; ++i)
#pragma unroll
            for (int j = 0; j < FN; ++j) acc[i][j] = floatx4{0.f, 0.f, 0.f, 0.f};

#pragma unroll 2
        for (int kt = 0; kt < NK; ++kt) {
            const int buf = kt & 1;
            if (kt + 1 < NK) {
                dma_tiles(kt + 1, 1 - buf);    // issue next batch FIRST
                if constexpr (A_REM == 0) {
                    wait_vmcnt<CNT>();
                } else {
                    if (w < A_REM) wait_vmcnt<CNT + 1>(); else wait_vmcnt<CNT>();
                }
            } else {
                wait_vmcnt<0>();               // epilogue drain
            }
            __builtin_amdgcn_s_barrier();      // tile kt visible to all waves
            asm volatile("" ::: "memory");     // no hoisting reads above barrier

            short8 av[2][FM], wv[2][FN];
#pragma unroll
            for (int kk = 0; kk < 2; ++kk) {
#pragma unroll
                for (int i = 0; i < FM; ++i) {
                    int m = wy * FM * 16 + i * 16 + lm;
                    int pc = (kk * 4 + quad) ^ (m & 7);
                    av[kk][i] = *(const short8*)&As[buf * ASZ + m * 64 + pc * 8];
                }
#pragma unroll
                for (int j = 0; j < FN; ++j) {
                    int n = wx * FN * 16 + j * 16 + lm;
                    int pc = (kk * 4 + quad) ^ (n & 7);
                    wv[kk][j] = *(const short8*)&Ws[buf * WSZ + n * 64 + pc * 8];
                }
            }
            asm volatile("s_waitcnt lgkmcnt(0)" ::: "memory");  // frag regs live
            __builtin_amdgcn_sched_barrier(0);
            __builtin_amdgcn_s_barrier();      // all readers done; buf reusable
            asm volatile("" ::: "memory");

            __builtin_amdgcn_s_setprio(1);
#pragma unroll
            for (int kk = 0; kk < 2; ++kk)
#pragma unroll
                for (int i = 0; i < FM; ++i)
#pragma unroll
                    for (int j = 0; j < FN; ++j)
                        acc[i][j] = __builtin_amdgcn_mfma_f32_16x16x32_bf16(
                            av[kk][i], wv[kk][j], acc[i][j], 0, 0, 0);
            __builtin_amdgcn_s_setprio(0);
        }

        // epilogue: bias + relu; C layout col=lane&15, row=quad*4+reg
#pragma unroll
        for (int i = 0; i < FM; ++i) {
#pragma unroll
            for (int rg = 0; rg < 4; ++rg) {
                int m = wy * FM * 16 + i * 16 + quad * 4 + rg;
                int p = row_start + m;
                if (p < bend) {
                    if constexpr (SCATTER) {
                        int orow = rowidx[p];
#pragma unroll
                        for (int j = 0; j < FN; ++j) {
                            int n = n0 + wx * FN * 16 + j * 16 + lm;
                            float v = acc[i][j][rg] + bias[j];
                            OutF[(size_t)orow * N + n] = v > 0.f ? v : 0.f;
                        }
                    } else {
#pragma unroll
                        for (int j = 0; j < FN; ++j) {
                            int n = n0 + wx * FN * 16 + j * 16 + lm;
                            float v = acc[i][j][rg] + bias[j];
                            OutB[(size_t)p * N + n] = f2bf(v > 0.f ? v : 0.f);
                        }
                    }
                }
            }
        }
    }
}

// ---------------------------------------------------------------------------
// Single cooperative kernel, 256 blocks x 512 threads. 48KB LDS -> 3
// blocks/CU occupancy limit, so 256 co-resident blocks have 3x margin:
// cooperative launch cannot over-subscribe (round-4 hang suspect removed).
// Grid syncs separate the 4 stages; __threadfence covers cross-XCD L2.
// ---------------------------------------------------------------------------
union SMemAll {
    unsigned short gemm[24576];        // 48KB: As/Ws double buffers
    unsigned short wtile[64 * 256];    // 32KB transpose buffer
    SortMem sort;                      // ~12.4KB
};

__launch_bounds__(512, 1)
__global__ void star_all(const float* __restrict__ x,
                         const int* __restrict__ ind,
                         const float* __restrict__ sk0, const float* __restrict__ dk0,
                         const float* __restrict__ sk1, const float* __restrict__ dk1,
                         const float* __restrict__ sk2, const float* __restrict__ dk2,
                         const float* __restrict__ sb0, const float* __restrict__ db0,
                         const float* __restrict__ sb1, const float* __restrict__ db1,
                         const float* __restrict__ sb2, const float* __restrict__ db2,
                         float* __restrict__ out,
                         unsigned short* __restrict__ xb,
                         unsigned short* __restrict__ h1,
                         unsigned short* __restrict__ h2,
                         unsigned short* __restrict__ w0t,
                         unsigned short* __restrict__ w1t,
                         unsigned short* __restrict__ w2t,
                         int* __restrict__ offsets,
                         int* __restrict__ rowidx) {
    __shared__ __align__(128) SMemAll smem;
    cg::grid_group grid = cg::this_grid();

    // ---- stage P: xb cvt + w0t/w1t/w2t transposes + sort (1089 work items)
    for (int item = blockIdx.x; item < 1089; item += 256) {
        if (item < 256) {
            xb_task(x, xb, item);
        } else if (item < 768) {
            weff_tile<1024, 1024>(sk0, dk0, w0t, smem.wtile, item - 256);
        } else if (item == 768) {
            sort_task(ind, offsets, rowidx, smem.sort);
        } else if (item < 1025) {
            weff_tile<1024, 512>(sk1, dk1, w1t, smem.wtile, item - 769);
        } else {
            weff_tile<512, 256>(sk2, dk2, w2t, smem.wtile, item - 1025);
        }
        __syncthreads();                       // LDS reuse across items
    }
    __threadfence();                           // device-scope: cross-XCD visibility
    grid.sync();

    // ---- stage 1: L0 GEMM, 64x128 tiles, 8d x 4slot x 8n = 256 blocks
    star_gemm_body<2, 2, 4, 1024, 1024, true, false>(
        smem.gemm, smem.gemm + 8192, xb, w0t, sb0, db0, nullptr, h1,
        offsets, rowidx, blockIdx.x);
    __threadfence();
    grid.sync();

    // ---- stage 2: L1 GEMM, 64x128 tiles, 8d x 8slot x 4n = 256 blocks
    star_gemm_body<2, 2, 8, 1024, 512, false, false>(
        smem.gemm, smem.gemm + 8192, h1, w1t, sb1, db1, nullptr, h2,
        offsets, rowidx, blockIdx.x);
    __threadfence();
    grid.sync();

    // ---- stage 3: L2 GEMM, 32x128 tiles, 8d x 16slot x 2n = 256 blocks
    star_gemm_body<1, 2, 16, 512, 256, false, true>(
        smem.gemm, smem.gemm + 4096, h2, w2t, sb2, db2, out, nullptr,
        offsets, rowidx, blockIdx.x);
}

extern "C" void kernel_launch(void* const* d_in, const int* in_sizes, int n_in,
                              void* d_out, int out_size, void* d_ws, size_t ws_size,
                              hipStream_t stream) {
    const float* x = (const float*)d_in[0];
    const int* ind = (const int*)d_in[1];
    const float* sk0 = (const float*)d_in[2];
    const float* sb0 = (const float*)d_in[3];
    const float* dk0 = (const float*)d_in[4];
    const float* db0 = (const float*)d_in[5];
    const float* sk1 = (const float*)d_in[6];
    const float* sb1 = (const float*)d_in[7];
    const float* dk1 = (const float*)d_in[8];
    const float* db1 = (const float*)d_in[9];
    const float* sk2 = (const float*)d_in[10];
    const float* sb2 = (const float*)d_in[11];
    const float* dk2 = (const float*)d_in[12];
    const float* db2 = (const float*)d_in[13];
    float* out = (float*)d_out;

    // workspace layout (~46 MB)
    char* ws = (char*)d_ws;
    int* offsets = (int*)ws;                                      // 64 B
    int* rowidx = (int*)(ws + 256);                               // 16 KB
    unsigned short* xb  = (unsigned short*)(ws + 32768);          // 8 MB  bf16 x, ORIGINAL order
    unsigned short* h1  = xb + (size_t)NROWS * 1024;              // 8 MB  bucket order
    unsigned short* h2  = h1 + (size_t)NROWS * 1024;              // 4 MB  bucket order
    unsigned short* w0t = h2 + (size_t)NROWS * 512;               // 16 MB [d][n=1024][k=1024]
    unsigned short* w1t = w0t + (size_t)NDOM * 1024 * 1024;       // 8 MB  [d][n=512][k=1024]
    unsigned short* w2t = w1t + (size_t)NDOM * 512 * 1024;        // 2 MB  [d][n=256][k=512]

    void* args[] = {
        (void*)&x, (void*)&ind,
        (void*)&sk0, (void*)&dk0, (void*)&sk1, (void*)&dk1, (void*)&sk2, (void*)&dk2,
        (void*)&sb0, (void*)&db0, (void*)&sb1, (void*)&db1, (void*)&sb2, (void*)&db2,
        (void*)&out,
        (void*)&xb, (void*)&h1, (void*)&h2,
        (void*)&w0t, (void*)&w1t, (void*)&w2t,
        (void*)&offsets, (void*)&rowidx
    };
    hipLaunchCooperativeKernel((void*)star_all, dim3(256), dim3(512),
                               args, 0, stream);
}

// Round 6
// 195.336 us; speedup vs baseline: 2.4088x; 2.4088x over previous
//
#include <hip/hip_runtime.h>

#define NROWS 4096
#define NDOM 8

typedef short short8 __attribute__((ext_vector_type(8)));
typedef float floatx4 __attribute__((ext_vector_type(4)));
typedef unsigned short ushort8v __attribute__((ext_vector_type(8)));

__device__ __forceinline__ unsigned short f2bf(float f) {
    union { float f; unsigned u; } v; v.f = f;
    unsigned r = v.u + 0x7FFFu + ((v.u >> 16) & 1u);  // RNE
    return (unsigned short)(r >> 16);
}

// async global->LDS, 16B per lane; dest = wave-uniform base + lane*16,
// source address may be per-lane (gather is legal on the source side).
__device__ __forceinline__ void dma16(const void* g, void* l) {
    __builtin_amdgcn_global_load_lds(
        (const __attribute__((address_space(1))) unsigned*)g,
        (__attribute__((address_space(3))) unsigned*)l, 16, 0, 0);
}

// counted vmcnt wait (immediate must be a literal in the asm string)
template <int N>
__device__ __forceinline__ void wait_vmcnt() {
    static_assert(N == 0 || N == 2 || N == 3 || N == 4 || N == 6 || N == 8, "unsupported vmcnt");
    if constexpr (N == 0) asm volatile("s_waitcnt vmcnt(0)" ::: "memory");
    else if constexpr (N == 2) asm volatile("s_waitcnt vmcnt(2)" ::: "memory");
    else if constexpr (N == 3) asm volatile("s_waitcnt vmcnt(3)" ::: "memory");
    else if constexpr (N == 4) asm volatile("s_waitcnt vmcnt(4)" ::: "memory");
    else if constexpr (N == 6) asm volatile("s_waitcnt vmcnt(6)" ::: "memory");
    else if constexpr (N == 8) asm volatile("s_waitcnt vmcnt(8)" ::: "memory");
}

// ---------------------------------------------------------------------------
// Fused precompute dispatch (identical to the 187µs-verified version):
//   blocks [0,256)        : xb = bf16(x), ORIGINAL row order
//   blocks [256,768)      : w0t = bf16(sk0*dk0) transposed [d][n][k]
//   blocks [768,1024)     : w1t
//   blocks [1024,1088)    : w2t
//   block 1088            : deterministic counting-sort -> offsets, rowidx
// ---------------------------------------------------------------------------

template <int K, int N>
__device__ __forceinline__ void weff_tile(const float* __restrict__ sk,
                                          const float* __restrict__ dk,
                                          unsigned short* __restrict__ wt,
                                          unsigned short* __restrict__ lds,
                                          int local) {
    const int d = local & 7;
    const int rest = local >> 3;
    const int k0 = (rest & (K / 256 - 1)) * 256;
    const int n0 = (rest / (K / 256)) * 64;
    const int t = threadIdx.x;

    // phase A: read n-coalesced, write LDS [n][k] with chunk-XOR swizzle
    const int n = t & 63;
    const int kg = (t >> 6) * 64;          // 4 k-groups of 64
#pragma unroll
    for (int c8 = 0; c8 < 8; ++c8) {       // 8 chunks of 8 k
        const int kb = k0 + kg + c8 * 8;
        unsigned short wb[8];
#pragma unroll
        for (int i = 0; i < 8; ++i) {
            int k = kb + i;
            wb[i] = f2bf(sk[(size_t)k * N + n0 + n] * dk[((size_t)d * K + k) * N + n0 + n]);
        }
        int ch = (kg + c8 * 8) >> 3;       // chunk index 0..31
        int phys = ch ^ (n & 31);
        *(ushort8v*)&lds[n * 256 + phys * 8] = *(ushort8v*)wb;
    }
    __syncthreads();

    // phase B: read LDS along k, store global [n][k] coalesced
#pragma unroll
    for (int it = 0; it < 4; ++it) {
        const int nn = (t >> 4) + it * 16;
        const int c = t & 15;              // 32B unit = 2 chunks
        ushort8v a = *(ushort8v*)&lds[nn * 256 + ((2 * c) ^ (nn & 31)) * 8];
        ushort8v b = *(ushort8v*)&lds[nn * 256 + ((2 * c + 1) ^ (nn & 31)) * 8];
        unsigned short* dst = wt + ((size_t)d * N + n0 + nn) * K + k0 + c * 16;
        *(ushort8v*)dst = a;
        *(ushort8v*)(dst + 8) = b;
    }
}

__global__ void precompute_kernel(const float* __restrict__ x,
                                  const int* __restrict__ ind,
                                  const float* __restrict__ sk0, const float* __restrict__ dk0,
                                  const float* __restrict__ sk1, const float* __restrict__ dk1,
                                  const float* __restrict__ sk2, const float* __restrict__ dk2,
                                  unsigned short* __restrict__ xb,
                                  unsigned short* __restrict__ w0t,
                                  unsigned short* __restrict__ w1t,
                                  unsigned short* __restrict__ w2t,
                                  int* __restrict__ offsets,
                                  int* __restrict__ rowidx) {
    __shared__ union SMem {
        unsigned short wtile[64 * 256];                 // 32KB transpose buffer
        struct {
            unsigned short cnt[256][NDOM];
            int base[256][NDOM];
            int dom_total[NDOM];
            int dom_off[NDOM + 1];
        } sort;
    } smem;

    const int b = blockIdx.x;
    const int t = threadIdx.x;

    if (b < 256) {
        // xb: bf16(x) in original row order, fully coalesced both sides
#pragma unroll
        for (int pass = 0; pass < 8; ++pass) {
            int row = b * 16 + pass * 2 + (t >> 7);
            int ch = t & 127;                       // 8-elem chunk
            const float* src = x + (size_t)row * 1024 + ch * 8;
            floatx4 v0 = *(const floatx4*)src;
            floatx4 v1 = *(const floatx4*)(src + 4);
            unsigned short o[8];
            o[0] = f2bf(v0[0]); o[1] = f2bf(v0[1]); o[2] = f2bf(v0[2]); o[3] = f2bf(v0[3]);
            o[4] = f2bf(v1[0]); o[5] = f2bf(v1[1]); o[6] = f2bf(v1[2]); o[7] = f2bf(v1[3]);
            *(ushort8v*)(xb + (size_t)row * 1024 + ch * 8) = *(ushort8v*)o;
        }
    } else if (b < 256 + 512) {
        weff_tile<1024, 1024>(sk0, dk0, w0t, smem.wtile, b - 256);
    } else if (b < 256 + 512 + 256) {
        weff_tile<1024, 512>(sk1, dk1, w1t, smem.wtile, b - (256 + 512));
    } else if (b < 256 + 512 + 256 + 64) {
        weff_tile<512, 256>(sk2, dk2, w2t, smem.wtile, b - (256 + 512 + 256));
    } else {
        // deterministic stable counting sort (pure function of `ind`)
        int myind[16];
#pragma unroll
        for (int i = 0; i < 16; ++i) myind[i] = ind[t * 16 + i];
        unsigned short c[NDOM];
#pragma unroll
        for (int d = 0; d < NDOM; ++d) c[d] = 0;
#pragma unroll
        for (int i = 0; i < 16; ++i) c[myind[i]]++;
#pragma unroll
        for (int d = 0; d < NDOM; ++d) smem.sort.cnt[t][d] = c[d];
        __syncthreads();
        if (t < NDOM) {
            int acc = 0;
            for (int ch = 0; ch < 256; ++ch) { smem.sort.base[ch][t] = acc; acc += smem.sort.cnt[ch][t]; }
            smem.sort.dom_total[t] = acc;
        }
        __syncthreads();
        if (t == 0) {
            int acc = 0;
            for (int d = 0; d < NDOM; ++d) { smem.sort.dom_off[d] = acc; acc += smem.sort.dom_total[d]; }
            smem.sort.dom_off[NDOM] = acc;
        }
        __syncthreads();
        int pos[NDOM];
#pragma unroll
        for (int d = 0; d < NDOM; ++d) pos[d] = smem.sort.dom_off[d] + smem.sort.base[t][d];
#pragma unroll
        for (int i = 0; i < 16; ++i) {
            int dm = myind[i];
            rowidx[pos[dm]++] = t * 16 + i;
        }
        if (t <= NDOM) offsets[t] = smem.sort.dom_off[t];
    }
}

// ---------------------------------------------------------------------------
// Grouped GEMM: 2x2 waves (256 thr), wave tile (FM*16)x(FN*16), TRIPLE-
// buffered LDS, prefetch depth 2. Round-5 isolated the stall: one batch in
// flight covers ~1 iteration (~250cy) but load latency is ~300cy(L2)/900(HBM)
// -> vmcnt blocked every k-tile. Depth-2 gives ~2 iterations of cover.
//   iter kt: issue dma(kt+2) -> vmcnt(2*CNT) [kt landed; kt+1,kt+2 flying]
//   -> barrier A -> ds_read frags(buf kt) -> lgkmcnt(0) -> barrier B -> MFMA
// Hazard: dma(kt+2) writes buf (kt+2)%3 == (kt-1)%3, whose readers all
// drained lgkm before barrier B(kt-1), which every wave passed before any
// wave reaches iter kt's dma issue -> safe (same proof as verified dbuf).
// ---------------------------------------------------------------------------
template <int FM, int FN, int MSLOTS, int K, int N, bool GATHER, bool SCATTER>
__launch_bounds__(256)
__global__ void star_gemm(const unsigned short* __restrict__ Ab,
                          const unsigned short* __restrict__ Wt,
                          const float* __restrict__ sb,
                          const float* __restrict__ db,
                          float* __restrict__ OutF,
                          unsigned short* __restrict__ OutB,
                          const int* __restrict__ offsets,
                          const int* __restrict__ rowidx) {
    constexpr int BM = 32 * FM;
    constexpr int BN = 32 * FN;
    constexpr int NK = K / 64;     // 64-wide k tiles
    constexpr int AI = BM / 32;    // A dma instrs per wave (1KB each)
    constexpr int WI = BN / 32;    // W dma instrs per wave
    constexpr int CNT = AI + WI;   // dma batch size per wave per k-tile
    constexpr int ASZ = BM * 64;
    constexpr int WSZ = BN * 64;

    __shared__ __align__(128) unsigned short As[3 * ASZ];
    __shared__ __align__(128) unsigned short Ws[3 * WSZ];

    const int gid = blockIdx.x;
    const int d = gid & 7;                      // domain -> XCD round-robin
    const int mslot = (gid >> 3) % MSLOTS;
    const int n0 = (gid / (8 * MSLOTS)) * BN;

    const int bstart = offsets[d];
    const int bend = offsets[d + 1];
    const int bsize = bend - bstart;

    const int tid = threadIdx.x;
    const int lane = tid & 63;
    const int w = tid >> 6;
    const int wy = w >> 1;
    const int wx = w & 1;
    const int lm = lane & 15;
    const int quad = lane >> 4;

    const int lrow = lane >> 3;    // DMA: row within 8-row group
    const int phys = lane & 7;     // DMA: physical LDS chunk

    float bias[FN];
#pragma unroll
    for (int j = 0; j < FN; ++j) {
        int n = n0 + wx * FN * 16 + j * 16 + lm;
        bias[j] = sb[n] + db[d * N + n];
    }

    // W dma sources (loop-invariant)
    const unsigned short* wsrc[WI];
#pragma unroll
    for (int j = 0; j < WI; ++j) {
        int nr0 = (w * WI + j) * 8;
        int nn = nr0 + lrow;
        int ch = phys ^ (nn & 7);
        wsrc[j] = Wt + ((size_t)d * N + n0 + nn) * K + ch * 8;
    }

    for (int mt = mslot; mt * BM < bsize; mt += MSLOTS) {
        const int row_start = bstart + mt * BM;

        const unsigned short* asrc[AI];
#pragma unroll
        for (int j = 0; j < AI; ++j) {
            int m0 = (w * AI + j) * 8;
            int mm = m0 + lrow;
            int ch = phys ^ (mm & 7);
            int p = row_start + mm; if (p >= bend) p = bend - 1;
            int src = GATHER ? rowidx[p] : p;
            asrc[j] = Ab + (size_t)src * K + ch * 8;
        }

        auto dma_tiles = [&](int kt, int buf) {
            const int k0 = kt * 64;
#pragma unroll
            for (int j = 0; j < AI; ++j)
                dma16(asrc[j] + k0, &As[buf * ASZ + (w * AI + j) * 512]);
#pragma unroll
            for (int j = 0; j < WI; ++j)
                dma16(wsrc[j] + k0, &Ws[buf * WSZ + (w * WI + j) * 512]);
        };

        dma_tiles(0, 0);                       // prologue: 2 batches in flight
        dma_tiles(1, 1);

        floatx4 acc[FM][FN];
#pragma unroll
        for (int i = 0; i < FM; ++i)
#pragma unroll
            for (int j = 0; j < FN; ++j) acc[i][j] = floatx4{0.f, 0.f, 0.f, 0.f};

        int buf = 0;
        for (int kt = 0; kt < NK; ++kt) {
            if (kt + 2 < NK) {
                int b2 = buf + 2; if (b2 >= 3) b2 -= 3;
                dma_tiles(kt + 2, b2);         // keep depth-2 in flight
                wait_vmcnt<2 * CNT>();         // batch kt landed
            } else if (kt + 1 < NK) {
                wait_vmcnt<CNT>();             // tail: kt landed, kt+1 flying
            } else {
                wait_vmcnt<0>();               // last tile drain
            }
            __builtin_amdgcn_s_barrier();      // tile kt visible to all waves
            asm volatile("" ::: "memory");     // no hoisting reads above barrier

            short8 av[2][FM], wv[2][FN];
#pragma unroll
            for (int kk = 0; kk < 2; ++kk) {
#pragma unroll
                for (int i = 0; i < FM; ++i) {
                    int m = wy * FM * 16 + i * 16 + lm;
                    int pc = (kk * 4 + quad) ^ (m & 7);
                    av[kk][i] = *(const short8*)&As[buf * ASZ + m * 64 + pc * 8];
                }
#pragma unroll
                for (int j = 0; j < FN; ++j) {
                    int n = wx * FN * 16 + j * 16 + lm;
                    int pc = (kk * 4 + quad) ^ (n & 7);
                    wv[kk][j] = *(const short8*)&Ws[buf * WSZ + n * 64 + pc * 8];
                }
            }
            asm volatile("s_waitcnt lgkmcnt(0)" ::: "memory");  // frag regs live
            __builtin_amdgcn_sched_barrier(0);
            __builtin_amdgcn_s_barrier();      // all readers done; buf reusable
            asm volatile("" ::: "memory");

            __builtin_amdgcn_s_setprio(1);
#pragma unroll
            for (int kk = 0; kk < 2; ++kk)
#pragma unroll
                for (int i = 0; i < FM; ++i)
#pragma unroll
                    for (int j = 0; j < FN; ++j)
                        acc[i][j] = __builtin_amdgcn_mfma_f32_16x16x32_bf16(
                            av[kk][i], wv[kk][j], acc[i][j], 0, 0, 0);
            __builtin_amdgcn_s_setprio(0);

            buf = (buf == 2) ? 0 : buf + 1;
        }

        // epilogue: bias + relu; C layout col=lane&15, row=quad*4+reg
#pragma unroll
        for (int i = 0; i < FM; ++i) {
#pragma unroll
            for (int rg = 0; rg < 4; ++rg) {
                int m = wy * FM * 16 + i * 16 + quad * 4 + rg;
                int p = row_start + m;
                if (p < bend) {
                    if constexpr (SCATTER) {
                        int orow = rowidx[p];
#pragma unroll
                        for (int j = 0; j < FN; ++j) {
                            int n = n0 + wx * FN * 16 + j * 16 + lm;
                            float v = acc[i][j][rg] + bias[j];
                            OutF[(size_t)orow * N + n] = v > 0.f ? v : 0.f;
                        }
                    } else {
#pragma unroll
                        for (int j = 0; j < FN; ++j) {
                            int n = n0 + wx * FN * 16 + j * 16 + lm;
                            float v = acc[i][j][rg] + bias[j];
                            OutB[(size_t)p * N + n] = f2bf(v > 0.f ? v : 0.f);
                        }
                    }
                }
            }
        }
    }
}

extern "C" void kernel_launch(void* const* d_in, const int* in_sizes, int n_in,
                              void* d_out, int out_size, void* d_ws, size_t ws_size,
                              hipStream_t stream) {
    const float* x = (const float*)d_in[0];
    const int* ind = (const int*)d_in[1];
    const float* sk0 = (const float*)d_in[2];
    const float* sb0 = (const float*)d_in[3];
    const float* dk0 = (const float*)d_in[4];
    const float* db0 = (const float*)d_in[5];
    const float* sk1 = (const float*)d_in[6];
    const float* sb1 = (const float*)d_in[7];
    const float* dk1 = (const float*)d_in[8];
    const float* db1 = (const float*)d_in[9];
    const float* sk2 = (const float*)d_in[10];
    const float* sb2 = (const float*)d_in[11];
    const float* dk2 = (const float*)d_in[12];
    const float* db2 = (const float*)d_in[13];
    float* out = (float*)d_out;

    // workspace layout (~46 MB)
    char* ws = (char*)d_ws;
    int* offsets = (int*)ws;                                      // 64 B
    int* rowidx = (int*)(ws + 256);                               // 16 KB
    unsigned short* xb  = (unsigned short*)(ws + 32768);          // 8 MB  bf16 x, ORIGINAL order
    unsigned short* h1  = xb + (size_t)NROWS * 1024;              // 8 MB  bucket order
    unsigned short* h2  = h1 + (size_t)NROWS * 1024;              // 4 MB  bucket order
    unsigned short* w0t = h2 + (size_t)NROWS * 512;               // 16 MB [d][n=1024][k=1024]
    unsigned short* w1t = w0t + (size_t)NDOM * 1024 * 1024;       // 8 MB  [d][n=512][k=1024]
    unsigned short* w2t = w1t + (size_t)NDOM * 512 * 1024;        // 2 MB  [d][n=256][k=512]

    // fused: xb cvt + 3x weight transpose-precompute + bucket sort (1 dispatch)
    precompute_kernel<<<256 + 512 + 256 + 64 + 1, 256, 0, stream>>>(
        x, ind, sk0, dk0, sk1, dk1, sk2, dk2, xb, w0t, w1t, w2t, offsets, rowidx);

    // L0: 64x64 tiles, 8d x 8m x 16n = 1024 blocks, rowidx-gather DMA
    star_gemm<2, 2, 8, 1024, 1024, true, false><<<1024, 256, 0, stream>>>(
        xb, w0t, sb0, db0, nullptr, h1, offsets, rowidx);
    // L1: 64x64 tiles, 8d x 8m x 8n = 512 blocks
    star_gemm<2, 2, 8, 1024, 512, false, false><<<512, 256, 0, stream>>>(
        h1, w1t, sb1, db1, nullptr, h2, offsets, rowidx);
    // L2: 32x64 tiles, 8d x 16m x 4n = 512 blocks (scatter to fp32 out)
    star_gemm<1, 2, 16, 512, 256, false, true><<<512, 256, 0, stream>>>(
        h2, w2t, sb2, db2, out, nullptr, offsets, rowidx);
}

// Round 7
// 191.030 us; speedup vs baseline: 2.4631x; 1.0225x over previous
//
#include <hip/hip_runtime.h>

#define NROWS 4096
#define NDOM 8

typedef short short8 __attribute__((ext_vector_type(8)));
typedef float floatx4 __attribute__((ext_vector_type(4)));
typedef unsigned short ushort8v __attribute__((ext_vector_type(8)));

__device__ __forceinline__ unsigned short f2bf(float f) {
    union { float f; unsigned u; } v; v.f = f;
    unsigned r = v.u + 0x7FFFu + ((v.u >> 16) & 1u);  // RNE
    return (unsigned short)(r >> 16);
}

// async global->LDS, 16B per lane; dest = wave-uniform base + lane*16,
// source address may be per-lane (gather is legal on the source side).
__device__ __forceinline__ void dma16(const void* g, void* l) {
    __builtin_amdgcn_global_load_lds(
        (const __attribute__((address_space(1))) unsigned*)g,
        (__attribute__((address_space(3))) unsigned*)l, 16, 0, 0);
}

// counted vmcnt wait (immediate must be a literal in the asm string)
template <int N>
__device__ __forceinline__ void wait_vmcnt() {
    static_assert(N == 0 || N == 2 || N == 3 || N == 4 || N == 6 || N == 8, "unsupported vmcnt");
    if constexpr (N == 0) asm volatile("s_waitcnt vmcnt(0)" ::: "memory");
    else if constexpr (N == 2) asm volatile("s_waitcnt vmcnt(2)" ::: "memory");
    else if constexpr (N == 3) asm volatile("s_waitcnt vmcnt(3)" ::: "memory");
    else if constexpr (N == 4) asm volatile("s_waitcnt vmcnt(4)" ::: "memory");
    else if constexpr (N == 6) asm volatile("s_waitcnt vmcnt(6)" ::: "memory");
    else if constexpr (N == 8) asm volatile("s_waitcnt vmcnt(8)" ::: "memory");
}

// ---------------------------------------------------------------------------
// weff transpose tile: (domain d, 64 n, 256 k) of bf16(sk*dk) -> wt[d][n][k].
// Round-6 PMC showed the OLD phase A was VMEM-issue-bound: 128 scalar 4B
// loads/thread = 106K issues/CU = the whole 44us. New phase A: each lane
// loads float4 over n (16B/lane): thread = (n-quad nq, k-octet ko), 8 k-rows
// x 2 float4 loads -> 32 issues/thread (4x fewer). Same LDS [n][k] chunk-XOR
// layout as before; phase B untouched.
// ---------------------------------------------------------------------------
template <int K, int N>
__device__ __forceinline__ void weff_tile(const float* __restrict__ sk,
                                          const float* __restrict__ dk,
                                          unsigned short* __restrict__ wt,
                                          unsigned short* __restrict__ lds,
                                          int local) {
    const int d = local & 7;
    const int rest = local >> 3;
    const int k0 = (rest & (K / 256 - 1)) * 256;
    const int n0 = (rest / (K / 256)) * 64;
    const int t = threadIdx.x;

    // phase A: float4 loads over n, per-thread 4n x 8k micro-tile
    const int nq = t & 15;             // n-quad: n = nq*4 + j
    const int ko = t >> 4;             // k-octet within iteration [0,16)
#pragma unroll
    for (int it = 0; it < 2; ++it) {
        const int ch = it * 16 + ko;   // chunk index 0..31 (8 k each)
        const int kb = k0 + ch * 8;
        unsigned short ob[4][8];       // [j][i] bf16 products
#pragma unroll
        for (int i = 0; i < 8; ++i) {
            const int k = kb + i;
            floatx4 sv = *(const floatx4*)&sk[(size_t)k * N + n0 + nq * 4];
            floatx4 dv = *(const floatx4*)&dk[((size_t)d * K + k) * N + n0 + nq * 4];
#pragma unroll
            for (int j = 0; j < 4; ++j) ob[j][i] = f2bf(sv[j] * dv[j]);
        }
#pragma unroll
        for (int j = 0; j < 4; ++j) {
            const int n = nq * 4 + j;
            const int phys = ch ^ (n & 31);
            *(ushort8v*)&lds[n * 256 + phys * 8] = *(ushort8v*)ob[j];
        }
    }
    __syncthreads();

    // phase B: read LDS along k, store global [n][k] coalesced
#pragma unroll
    for (int it = 0; it < 4; ++it) {
        const int nn = (t >> 4) + it * 16;
        const int c = t & 15;              // 32B unit = 2 chunks
        ushort8v a = *(ushort8v*)&lds[nn * 256 + ((2 * c) ^ (nn & 31)) * 8];
        ushort8v b = *(ushort8v*)&lds[nn * 256 + ((2 * c + 1) ^ (nn & 31)) * 8];
        unsigned short* dst = wt + ((size_t)d * N + n0 + nn) * K + k0 + c * 16;
        *(ushort8v*)dst = a;
        *(ushort8v*)(dst + 8) = b;
    }
}

// ---------------------------------------------------------------------------
// Fused precompute dispatch:
//   blocks [0,256)        : xb = bf16(x), ORIGINAL row order
//   blocks [256,768)      : w0t transpose
//   blocks [768,1024)     : w1t
//   blocks [1024,1088)    : w2t
//   block 1088            : deterministic counting-sort -> offsets, rowidx
// ---------------------------------------------------------------------------
__global__ void precompute_kernel(const float* __restrict__ x,
                                  const int* __restrict__ ind,
                                  const float* __restrict__ sk0, const float* __restrict__ dk0,
                                  const float* __restrict__ sk1, const float* __restrict__ dk1,
                                  const float* __restrict__ sk2, const float* __restrict__ dk2,
                                  unsigned short* __restrict__ xb,
                                  unsigned short* __restrict__ w0t,
                                  unsigned short* __restrict__ w1t,
                                  unsigned short* __restrict__ w2t,
                                  int* __restrict__ offsets,
                                  int* __restrict__ rowidx) {
    __shared__ union SMem {
        unsigned short wtile[64 * 256];                 // 32KB transpose buffer
        struct {
            unsigned short cnt[256][NDOM];
            int base[256][NDOM];
            int dom_total[NDOM];
            int dom_off[NDOM + 1];
        } sort;
    } smem;

    const int b = blockIdx.x;
    const int t = threadIdx.x;

    if (b < 256) {
        // xb: bf16(x) in original row order, fully coalesced both sides
#pragma unroll
        for (int pass = 0; pass < 8; ++pass) {
            int row = b * 16 + pass * 2 + (t >> 7);
            int ch = t & 127;                       // 8-elem chunk
            const float* src = x + (size_t)row * 1024 + ch * 8;
            floatx4 v0 = *(const floatx4*)src;
            floatx4 v1 = *(const floatx4*)(src + 4);
            unsigned short o[8];
            o[0] = f2bf(v0[0]); o[1] = f2bf(v0[1]); o[2] = f2bf(v0[2]); o[3] = f2bf(v0[3]);
            o[4] = f2bf(v1[0]); o[5] = f2bf(v1[1]); o[6] = f2bf(v1[2]); o[7] = f2bf(v1[3]);
            *(ushort8v*)(xb + (size_t)row * 1024 + ch * 8) = *(ushort8v*)o;
        }
    } else if (b < 256 + 512) {
        weff_tile<1024, 1024>(sk0, dk0, w0t, smem.wtile, b - 256);
    } else if (b < 256 + 512 + 256) {
        weff_tile<1024, 512>(sk1, dk1, w1t, smem.wtile, b - (256 + 512));
    } else if (b < 256 + 512 + 256 + 64) {
        weff_tile<512, 256>(sk2, dk2, w2t, smem.wtile, b - (256 + 512 + 256));
    } else {
        // deterministic stable counting sort (pure function of `ind`)
        int myind[16];
#pragma unroll
        for (int i = 0; i < 16; ++i) myind[i] = ind[t * 16 + i];
        unsigned short c[NDOM];
#pragma unroll
        for (int d = 0; d < NDOM; ++d) c[d] = 0;
#pragma unroll
        for (int i = 0; i < 16; ++i) c[myind[i]]++;
#pragma unroll
        for (int d = 0; d < NDOM; ++d) smem.sort.cnt[t][d] = c[d];
        __syncthreads();
        if (t < NDOM) {
            int acc = 0;
            for (int ch = 0; ch < 256; ++ch) { smem.sort.base[ch][t] = acc; acc += smem.sort.cnt[ch][t]; }
            smem.sort.dom_total[t] = acc;
        }
        __syncthreads();
        if (t == 0) {
            int acc = 0;
            for (int d = 0; d < NDOM; ++d) { smem.sort.dom_off[d] = acc; acc += smem.sort.dom_total[d]; }
            smem.sort.dom_off[NDOM] = acc;
        }
        __syncthreads();
        int pos[NDOM];
#pragma unroll
        for (int d = 0; d < NDOM; ++d) pos[d] = smem.sort.dom_off[d] + smem.sort.base[t][d];
#pragma unroll
        for (int i = 0; i < 16; ++i) {
            int dm = myind[i];
            rowidx[pos[dm]++] = t * 16 + i;
        }
        if (t <= NDOM) offsets[t] = smem.sort.dom_off[t];
    }
}

// ---------------------------------------------------------------------------
// Grouped GEMM: 2x2 waves, wave tile (FM*16)x(FN*16), double-buffered LDS
// (32KB -> 5 blocks/CU), counted-vmcnt pipeline (round-2-verified).
// ---------------------------------------------------------------------------
template <int FM, int FN, int MSLOTS, int K, int N, bool GATHER, bool SCATTER>
__launch_bounds__(256)
__global__ void star_gemm(const unsigned short* __restrict__ Ab,
                          const unsigned short* __restrict__ Wt,
                          const float* __restrict__ sb,
                          const float* __restrict__ db,
                          float* __restrict__ OutF,
                          unsigned short* __restrict__ OutB,
                          const int* __restrict__ offsets,
                          const int* __restrict__ rowidx) {
    constexpr int BM = 32 * FM;
    constexpr int BN = 32 * FN;
    constexpr int NK = K / 64;     // 64-wide k tiles (NK even)
    constexpr int AI = BM / 32;    // A dma instrs per wave (1KB each)
    constexpr int WI = BN / 32;    // W dma instrs per wave
    constexpr int CNT = AI + WI;   // dma batch size per wave per k-tile

    __shared__ __align__(128) unsigned short As[2][BM * 64];
    __shared__ __align__(128) unsigned short Ws[2][BN * 64];

    const int gid = blockIdx.x;
    const int d = gid & 7;                      // domain -> XCD round-robin
    const int mslot = (gid >> 3) % MSLOTS;
    const int n0 = (gid / (8 * MSLOTS)) * BN;

    const int bstart = offsets[d];
    const int bend = offsets[d + 1];
    const int bsize = bend - bstart;

    const int tid = threadIdx.x;
    const int lane = tid & 63;
    const int w = tid >> 6;
    const int wy = w >> 1;
    const int wx = w & 1;
    const int lm = lane & 15;
    const int quad = lane >> 4;

    const int lrow = lane >> 3;    // DMA: row within 8-row group
    const int phys = lane & 7;     // DMA: physical LDS chunk

    float bias[FN];
#pragma unroll
    for (int j = 0; j < FN; ++j) {
        int n = n0 + wx * FN * 16 + j * 16 + lm;
        bias[j] = sb[n] + db[d * N + n];
    }

    // W dma sources (loop-invariant)
    const unsigned short* wsrc[WI];
#pragma unroll
    for (int j = 0; j < WI; ++j) {
        int nr0 = (w * WI + j) * 8;
        int nn = nr0 + lrow;
        int ch = phys ^ (nn & 7);
        wsrc[j] = Wt + ((size_t)d * N + n0 + nn) * K + ch * 8;
    }

    for (int mt = mslot; mt * BM < bsize; mt += MSLOTS) {
        const int row_start = bstart + mt * BM;

        const unsigned short* asrc[AI];
#pragma unroll
        for (int j = 0; j < AI; ++j) {
            int m0 = (w * AI + j) * 8;
            int mm = m0 + lrow;
            int ch = phys ^ (mm & 7);
            int p = row_start + mm; if (p >= bend) p = bend - 1;
            int src = GATHER ? rowidx[p] : p;
            asrc[j] = Ab + (size_t)src * K + ch * 8;
        }

        auto dma_tiles = [&](int kt, int buf) {
            const int k0 = kt * 64;
#pragma unroll
            for (int j = 0; j < AI; ++j)
                dma16(asrc[j] + k0, &As[buf][(w * AI + j) * 512]);
#pragma unroll
            for (int j = 0; j < WI; ++j)
                dma16(wsrc[j] + k0, &Ws[buf][(w * WI + j) * 512]);
        };

        dma_tiles(0, 0);                       // prologue batch in flight

        floatx4 acc[FM][FN];
#pragma unroll
        for (int i = 0; i < FM; ++i)
#pragma unroll
            for (int j = 0; j < FN; ++j) acc[i][j] = floatx4{0.f, 0.f, 0.f, 0.f};

#pragma unroll 2
        for (int kt = 0; kt < NK; ++kt) {
            const int buf = kt & 1;
            if (kt + 1 < NK) {
                dma_tiles(kt + 1, 1 - buf);    // issue next batch FIRST
                wait_vmcnt<CNT>();             // tile kt arrived; kt+1 stays in flight
            } else {
                wait_vmcnt<0>();               // epilogue drain
            }
            __builtin_amdgcn_s_barrier();      // tile kt visible to all waves
            asm volatile("" ::: "memory");     // no hoisting reads above barrier

            short8 av[2][FM], wv[2][FN];
#pragma unroll
            for (int kk = 0; kk < 2; ++kk) {
#pragma unroll
                for (int i = 0; i < FM; ++i) {
                    int m = wy * FM * 16 + i * 16 + lm;
                    int pc = (kk * 4 + quad) ^ (m & 7);
                    av[kk][i] = *(const short8*)&As[buf][m * 64 + pc * 8];
                }
#pragma unroll
                for (int j = 0; j < FN; ++j) {
                    int n = wx * FN * 16 + j * 16 + lm;
                    int pc = (kk * 4 + quad) ^ (n & 7);
                    wv[kk][j] = *(const short8*)&Ws[buf][n * 64 + pc * 8];
                }
            }
            asm volatile("s_waitcnt lgkmcnt(0)" ::: "memory");  // frag regs live
            __builtin_amdgcn_sched_barrier(0);
            __builtin_amdgcn_s_barrier();      // all readers done; buf reusable
            asm volatile("" ::: "memory");

            __builtin_amdgcn_s_setprio(1);
#pragma unroll
            for (int kk = 0; kk < 2; ++kk)
#pragma unroll
                for (int i = 0; i < FM; ++i)
#pragma unroll
                    for (int j = 0; j < FN; ++j)
                        acc[i][j] = __builtin_amdgcn_mfma_f32_16x16x32_bf16(
                            av[kk][i], wv[kk][j], acc[i][j], 0, 0, 0);
            __builtin_amdgcn_s_setprio(0);
        }

        // epilogue: bias + relu; C layout col=lane&15, row=quad*4+reg
#pragma unroll
        for (int i = 0; i < FM; ++i) {
#pragma unroll
            for (int rg = 0; rg < 4; ++rg) {
                int m = wy * FM * 16 + i * 16 + quad * 4 + rg;
                int p = row_start + m;
                if (p < bend) {
                    if constexpr (SCATTER) {
                        int orow = rowidx[p];
#pragma unroll
                        for (int j = 0; j < FN; ++j) {
                            int n = n0 + wx * FN * 16 + j * 16 + lm;
                            float v = acc[i][j][rg] + bias[j];
                            OutF[(size_t)orow * N + n] = v > 0.f ? v : 0.f;
                        }
                    } else {
#pragma unroll
                        for (int j = 0; j < FN; ++j) {
                            int n = n0 + wx * FN * 16 + j * 16 + lm;
                            float v = acc[i][j][rg] + bias[j];
                            OutB[(size_t)p * N + n] = f2bf(v > 0.f ? v : 0.f);
                        }
                    }
                }
            }
        }
    }
}

extern "C" void kernel_launch(void* const* d_in, const int* in_sizes, int n_in,
                              void* d_out, int out_size, void* d_ws, size_t ws_size,
                              hipStream_t stream) {
    const float* x = (const float*)d_in[0];
    const int* ind = (const int*)d_in[1];
    const float* sk0 = (const float*)d_in[2];
    const float* sb0 = (const float*)d_in[3];
    const float* dk0 = (const float*)d_in[4];
    const float* db0 = (const float*)d_in[5];
    const float* sk1 = (const float*)d_in[6];
    const float* sb1 = (const float*)d_in[7];
    const float* dk1 = (const float*)d_in[8];
    const float* db1 = (const float*)d_in[9];
    const float* sk2 = (const float*)d_in[10];
    const float* sb2 = (const float*)d_in[11];
    const float* dk2 = (const float*)d_in[12];
    const float* db2 = (const float*)d_in[13];
    float* out = (float*)d_out;

    // workspace layout (~46 MB)
    char* ws = (char*)d_ws;
    int* offsets = (int*)ws;                                      // 64 B
    int* rowidx = (int*)(ws + 256);                               // 16 KB
    unsigned short* xb  = (unsigned short*)(ws + 32768);          // 8 MB  bf16 x, ORIGINAL order
    unsigned short* h1  = xb + (size_t)NROWS * 1024;              // 8 MB  bucket order
    unsigned short* h2  = h1 + (size_t)NROWS * 1024;              // 4 MB  bucket order
    unsigned short* w0t = h2 + (size_t)NROWS * 512;               // 16 MB [d][n=1024][k=1024]
    unsigned short* w1t = w0t + (size_t)NDOM * 1024 * 1024;       // 8 MB  [d][n=512][k=1024]
    unsigned short* w2t = w1t + (size_t)NDOM * 512 * 1024;        // 2 MB  [d][n=256][k=512]

    // fused: xb cvt + 3x weight transpose-precompute + bucket sort (1 dispatch)
    precompute_kernel<<<256 + 512 + 256 + 64 + 1, 256, 0, stream>>>(
        x, ind, sk0, dk0, sk1, dk1, sk2, dk2, xb, w0t, w1t, w2t, offsets, rowidx);

    // L0: 64x64 tiles, 8d x 8m x 16n = 1024 blocks, rowidx-gather DMA
    star_gemm<2, 2, 8, 1024, 1024, true, false><<<1024, 256, 0, stream>>>(
        xb, w0t, sb0, db0, nullptr, h1, offsets, rowidx);
    // L1: 64x64 tiles, 8d x 8m x 8n = 512 blocks
    star_gemm<2, 2, 8, 1024, 512, false, false><<<512, 256, 0, stream>>>(
        h1, w1t, sb1, db1, nullptr, h2, offsets, rowidx);
    // L2: 32x64 tiles, 8d x 16m x 4n = 512 blocks (scatter to fp32 out)
    star_gemm<1, 2, 16, 512, 256, false, true><<<512, 256, 0, stream>>>(
        h2, w2t, sb2, db2, out, nullptr, offsets, rowidx);
}